// Round 1
// baseline (355.464 us; speedup 1.0000x reference)
//
#include <hip/hip_runtime.h>
#include <cstdint>
#include <cstddef>
#include <math.h>

#define NTOK 8192
#define NEXP 64
#define MDIM 1024
#define CAP  256

// ---- d_out layout (floats) ----
// [0]                     l_aux
// [1 .. 1+NTOK*NEXP*CAP)  combine_weights
// [.. + NTOK*NEXP*CAP)    dispatch_mask (0.0/1.0)
// [.. + NEXP)             exp_counts (as float)
static const size_t OFF_CW = 1;
static const size_t OFF_DM = 1 + (size_t)NTOK * NEXP * CAP;
static const size_t OFF_EC = 1 + 2 * (size_t)NTOK * NEXP * CAP;

// ---- ws layout (4-byte elements) ----
#define WS_LOGITS 0                       // float [NTOK*NEXP]
#define WS_IDX1   (NTOK*NEXP)             // int   [NTOK]
#define WS_IDX2   (WS_IDX1 + NTOK)        // int   [NTOK]
#define WS_G1     (WS_IDX2 + NTOK)        // float [NTOK]
#define WS_G2     (WS_G1 + NTOK)          // float [NTOK]
#define WS_LOC1   (WS_G2 + NTOK)          // int   [NTOK]
#define WS_LOC2   (WS_LOC1 + NTOK)        // int   [NTOK]
#define WS_BPART  (WS_LOC2 + NTOK)        // float [128*64] per-block gate column sums
#define WS_CNT1   (WS_BPART + 128*64)     // int   [NEXP]

// ============================================================
// Kernel A: logits = x @ w^T   (M=8192, N=64, K=1024), fp32 VALU
// BM=64 tokens/block, BN=64 (all experts), BK=32. 256 threads, 4x4 micro-tile.
// ============================================================
__global__ __launch_bounds__(256) void k_gemm(const float* __restrict__ x,
                                              const float* __restrict__ w,
                                              float* __restrict__ logits) {
    __shared__ float as[32][65];  // as[k][m], +1 pad: conflict-free writes
    __shared__ float bs[32][65];  // bs[k][n]
    const int tid = threadIdx.x;
    const int m0 = blockIdx.x * 64;
    const int tm = (tid / 16) * 4;
    const int tn = (tid % 16) * 4;
    float acc[4][4] = {};

    for (int k0 = 0; k0 < MDIM; k0 += 32) {
        #pragma unroll
        for (int r = 0; r < 8; r++) {
            int idx = tid + r * 256;       // 0..2047
            int mm = idx >> 5;             // 0..63
            int kk = idx & 31;
            as[kk][mm] = x[(size_t)(m0 + mm) * MDIM + k0 + kk];
            bs[kk][mm] = w[(size_t)mm * MDIM + k0 + kk];
        }
        __syncthreads();
        #pragma unroll
        for (int kk = 0; kk < 32; kk++) {
            float a0 = as[kk][tm + 0], a1 = as[kk][tm + 1], a2 = as[kk][tm + 2], a3 = as[kk][tm + 3];
            float b0 = bs[kk][tn + 0], b1 = bs[kk][tn + 1], b2 = bs[kk][tn + 2], b3 = bs[kk][tn + 3];
            acc[0][0] += a0 * b0; acc[0][1] += a0 * b1; acc[0][2] += a0 * b2; acc[0][3] += a0 * b3;
            acc[1][0] += a1 * b0; acc[1][1] += a1 * b1; acc[1][2] += a1 * b2; acc[1][3] += a1 * b3;
            acc[2][0] += a2 * b0; acc[2][1] += a2 * b1; acc[2][2] += a2 * b2; acc[2][3] += a2 * b3;
            acc[3][0] += a3 * b0; acc[3][1] += a3 * b1; acc[3][2] += a3 * b2; acc[3][3] += a3 * b3;
        }
        __syncthreads();
    }
    #pragma unroll
    for (int i = 0; i < 4; i++)
        #pragma unroll
        for (int j = 0; j < 4; j++)
            logits[(size_t)(m0 + tm + i) * NEXP + tn + j] = acc[i][j];
}

// ============================================================
// Kernel B: per-token gating. 1 wave (64 lanes = 64 experts) per token.
// Block = 256 thr = 4 waves; block handles 64 tokens (16 per wave).
// Also produces deterministic per-block gate column-sum partials.
// ============================================================
__global__ __launch_bounds__(256) void k_gate(const float* __restrict__ logits,
                                              const float* __restrict__ gumbel,
                                              int* __restrict__ idx1, int* __restrict__ idx2,
                                              float* __restrict__ g1, float* __restrict__ g2,
                                              float* __restrict__ bpart) {
    const int wave = threadIdx.x >> 6;
    const int lane = threadIdx.x & 63;
    const int tbase = blockIdx.x * 64;
    float gacc = 0.f;

    for (int i = 0; i < 16; i++) {
        const int t = tbase + wave + i * 4;
        const float logit = logits[(size_t)t * NEXP + lane];

        // softmax (stable)
        float m = logit;
        #pragma unroll
        for (int off = 32; off; off >>= 1) m = fmaxf(m, __shfl_xor(m, off));
        const float p = expf(logit - m);
        float s = p;
        #pragma unroll
        for (int off = 32; off; off >>= 1) s += __shfl_xor(s, off);
        const float gate = p / s;

        // argmax over logits (== argmax gates), tie -> lowest index
        float v1 = logit; int b1 = lane;
        #pragma unroll
        for (int off = 32; off; off >>= 1) {
            float ov = __shfl_xor(v1, off); int oi = __shfl_xor(b1, off);
            if (ov > v1 || (ov == v1 && oi < b1)) { v1 = ov; b1 = oi; }
        }
        const int i1 = b1;

        // second choice: argmax of logits+gumbel with first masked to -inf
        float z = logit + gumbel[(size_t)t * NEXP + lane];
        if (lane == i1) z = -INFINITY;
        float v2 = z; int b2 = lane;
        #pragma unroll
        for (int off = 32; off; off >>= 1) {
            float ov = __shfl_xor(v2, off); int oi = __shfl_xor(b2, off);
            if (ov > v2 || (ov == v2 && oi < b2)) { v2 = ov; b2 = oi; }
        }
        const int i2 = b2;

        const float gg1 = __shfl(gate, i1);
        const float gg2 = __shfl(gate, i2);
        if (lane == 0) { idx1[t] = i1; idx2[t] = i2; g1[t] = gg1; g2[t] = gg2; }
        gacc += gate;   // lane == expert: column partial
    }

    __shared__ float sgs[4][64];
    sgs[wave][lane] = gacc;
    __syncthreads();
    if (threadIdx.x < 64) {
        float tsum = sgs[0][threadIdx.x] + sgs[1][threadIdx.x] + sgs[2][threadIdx.x] + sgs[3][threadIdx.x];
        bpart[(size_t)blockIdx.x * 64 + threadIdx.x] = tsum;  // deterministic partial
    }
}

// ============================================================
// Kernel C: per-expert exclusive prefix counts over token order.
// 1 wave per expert; ballot+popcount over 8192 tokens (x2 passes).
// loc2 includes +count1(total) offset per reference.
// ============================================================
__global__ __launch_bounds__(64) void k_scan(const int* __restrict__ idx1, const int* __restrict__ idx2,
                                             int* __restrict__ loc1, int* __restrict__ loc2,
                                             float* __restrict__ ec_out, int* __restrict__ cnt1_buf) {
    const int e = blockIdx.x;
    const int lane = threadIdx.x;
    const unsigned long long below = (lane == 63) ? 0x7FFFFFFFFFFFFFFFULL : ((1ULL << lane) - 1ULL);

    int cnt = 0;
    for (int base = 0; base < NTOK; base += 64) {
        const int t = base + lane;
        const bool m = (idx1[t] == e);
        const unsigned long long bal = __ballot(m);
        if (m) loc1[t] = cnt + __popcll(bal & below);
        cnt += __popcll(bal);
    }
    if (lane == 0) { cnt1_buf[e] = cnt; ec_out[e] = (float)cnt; }
    const int cnt1_total = cnt;

    int c2 = 0;
    for (int base = 0; base < NTOK; base += 64) {
        const int t = base + lane;
        const bool m = (idx2[t] == e);
        const unsigned long long bal = __ballot(m);
        if (m) loc2[t] = cnt1_total + c2 + __popcll(bal & below);
        c2 += __popcll(bal);
    }
}

// ============================================================
// Kernel D: normalize (post-capacity, per reference order) + scatter.
// ============================================================
__global__ __launch_bounds__(256) void k_scatter(const int* __restrict__ idx1, const int* __restrict__ idx2,
                                                 const int* __restrict__ loc1, const int* __restrict__ loc2,
                                                 const float* __restrict__ g1, const float* __restrict__ g2,
                                                 float* __restrict__ out) {
    const int t = blockIdx.x * 256 + threadIdx.x;
    const int i1 = idx1[t], i2 = idx2[t];
    const int l1 = loc1[t], l2 = loc2[t];
    const bool k1 = (l1 < CAP), k2 = (l2 < CAP);
    const float ga = k1 ? g1[t] : 0.f;
    const float gb = k2 ? g2[t] : 0.f;
    const float denom = fmaxf(ga + gb, 1.1920928955078125e-07f);  // f32 eps
    const float w1 = ga / denom;
    const float w2 = gb / denom;

    if (k1 && w1 != 0.f) {
        const size_t idx = (size_t)t * (NEXP * CAP) + (size_t)i1 * CAP + l1;
        out[OFF_CW + idx] = w1;
        out[OFF_DM + idx] = 1.0f;
    }
    if (k2 && w2 != 0.f) {
        const size_t idx = (size_t)t * (NEXP * CAP) + (size_t)i2 * CAP + l2;
        out[OFF_CW + idx] = w2;
        out[OFF_DM + idx] = 1.0f;
    }
}

// ============================================================
// Kernel E: l_aux = e * sum_e(me[e]*ce[e]) ; me = colsum/s, ce = cnt1/s.
// Fixed-order reduction -> deterministic.
// ============================================================
__global__ __launch_bounds__(64) void k_laux(const float* __restrict__ bpart,
                                             const int* __restrict__ cnt1,
                                             float* __restrict__ out) {
    const int lane = threadIdx.x;
    float s = 0.f;
    for (int b = 0; b < 128; b++) s += bpart[(size_t)b * 64 + lane];
    float v = s * (float)cnt1[lane];
    #pragma unroll
    for (int off = 32; off; off >>= 1) v += __shfl_xor(v, off);
    if (lane == 0) out[0] = 64.0f * v / ((float)NTOK * (float)NTOK);
}

extern "C" void kernel_launch(void* const* d_in, const int* in_sizes, int n_in,
                              void* d_out, int out_size, void* d_ws, size_t ws_size,
                              hipStream_t stream) {
    const float* x      = (const float*)d_in[0];
    const float* w      = (const float*)d_in[1];
    const float* gumbel = (const float*)d_in[2];
    float* out = (float*)d_out;

    float* ws_f = (float*)d_ws;
    int*   ws_i = (int*)d_ws;

    float* logits = ws_f + WS_LOGITS;
    int*   idx1   = ws_i + WS_IDX1;
    int*   idx2   = ws_i + WS_IDX2;
    float* g1     = ws_f + WS_G1;
    float* g2     = ws_f + WS_G2;
    int*   loc1   = ws_i + WS_LOC1;
    int*   loc2   = ws_i + WS_LOC2;
    float* bpart  = ws_f + WS_BPART;
    int*   cnt1   = ws_i + WS_CNT1;

    // Clear the whole output (combine zeros + dispatch false + l_aux + counts).
    hipMemsetAsync(d_out, 0, (size_t)out_size * sizeof(float), stream);

    k_gemm<<<NTOK / 64, 256, 0, stream>>>(x, w, logits);
    k_gate<<<NTOK / 64, 256, 0, stream>>>(logits, gumbel, idx1, idx2, g1, g2, bpart);
    k_scan<<<NEXP, 64, 0, stream>>>(idx1, idx2, loc1, loc2, out + OFF_EC, cnt1);
    k_scatter<<<NTOK / 256, 256, 0, stream>>>(idx1, idx2, loc1, loc2, g1, g2, out);
    k_laux<<<1, 64, 0, stream>>>(bpart, cnt1, out);
}

// Round 4
// 267.598 us; speedup vs baseline: 1.3284x; 1.3284x over previous
//
#include <hip/hip_runtime.h>
#include <cstdint>
#include <cstddef>
#include <math.h>

#define NTOK 8192
#define NEXP 64
#define MDIM 1024
#define CAP  256

#define GEMM_BLOCKS 128
#define FILL_BLOCKS 896
#define TOTAL_BLOCKS (GEMM_BLOCKS + FILL_BLOCKS)

typedef float f32x4 __attribute__((ext_vector_type(4)));

// ---- d_out layout (floats) ----
static const size_t OFF_CW = 1;
static const size_t OFF_DM = 1 + (size_t)NTOK * NEXP * CAP;
static const size_t OFF_EC = 1 + 2 * (size_t)NTOK * NEXP * CAP;
#define OUT_TOTAL (1 + 2 * (size_t)NTOK * NEXP * CAP + NEXP)

// ---- ws layout (4-byte elements) ----
#define WS_IDX1   0                       // int   [NTOK]
#define WS_IDX2   (WS_IDX1 + NTOK)        // int   [NTOK]
#define WS_G1     (WS_IDX2 + NTOK)        // float [NTOK]
#define WS_G2     (WS_G1 + NTOK)          // float [NTOK]
#define WS_LOC1   (WS_G2 + NTOK)          // int   [NTOK]
#define WS_LOC2   (WS_LOC1 + NTOK)        // int   [NTOK]
#define WS_BPART  (WS_LOC2 + NTOK)        // float [GEMM_BLOCKS*64]
#define WS_CNT1   (WS_BPART + GEMM_BLOCKS*64) // int [NEXP]

// ============================================================
// K1: block-specialized fused kernel.
//   blocks [0, GEMM_BLOCKS):            GEMM (64 tok x 64 exp tile) + inline gating
//   blocks [GEMM_BLOCKS, TOTAL_BLOCKS): grid-stride float4 zero-fill of d_out
// Fill (~175 us, BW-bound) hides GEMM+gate (~40 us, VALU-bound).
// ============================================================
__global__ __launch_bounds__(256) void k_main(const float* __restrict__ x,
                                              const float* __restrict__ w,
                                              const float* __restrict__ gumbel,
                                              int* __restrict__ idx1, int* __restrict__ idx2,
                                              float* __restrict__ g1, float* __restrict__ g2,
                                              float* __restrict__ bpart,
                                              float* __restrict__ out) {
    const int bid = blockIdx.x;
    const int tid = threadIdx.x;

    if (bid >= GEMM_BLOCKS) {
        // ---------------- fill path ----------------
        const size_t n4 = OUT_TOTAL / 4;            // float4 count (tail handled below)
        const f32x4 z = {0.f, 0.f, 0.f, 0.f};
        f32x4* o4 = (f32x4*)out;
        const int fb = bid - GEMM_BLOCKS;
        size_t i = (size_t)fb * 256 + tid;
        const size_t stride = (size_t)FILL_BLOCKS * 256;
        for (; i < n4; i += stride) __builtin_nontemporal_store(z, &o4[i]);
        if (fb == 0 && tid == 0) {
            for (size_t j = n4 * 4; j < OUT_TOTAL; j++) out[j] = 0.f;  // 1-elem tail
        }
        return;
    }

    // ---------------- GEMM + gate path ----------------
    __shared__ float as[32][68];   // [k][m], pad 68 keeps float4 reads 16B-aligned
    __shared__ float bs[32][68];   // [k][n]
    __shared__ float lt[64][65];   // logits tile [token][expert]
    __shared__ float sgs[4][64];

    const int m0 = bid * 64;
    const int tm = (tid / 16) * 4;
    const int tn = (tid % 16) * 4;
    float acc[4][4] = {};

    for (int k0 = 0; k0 < MDIM; k0 += 32) {
        #pragma unroll
        for (int r = 0; r < 2; r++) {
            const int idx = tid + r * 256;   // 0..511
            const int row = idx >> 3;        // 0..63
            const int kq  = idx & 7;         // float4 index in k
            const float4 va = *(const float4*)&x[(size_t)(m0 + row) * MDIM + k0 + kq * 4];
            as[kq * 4 + 0][row] = va.x; as[kq * 4 + 1][row] = va.y;
            as[kq * 4 + 2][row] = va.z; as[kq * 4 + 3][row] = va.w;
            const float4 vb = *(const float4*)&w[(size_t)row * MDIM + k0 + kq * 4];
            bs[kq * 4 + 0][row] = vb.x; bs[kq * 4 + 1][row] = vb.y;
            bs[kq * 4 + 2][row] = vb.z; bs[kq * 4 + 3][row] = vb.w;
        }
        __syncthreads();
        #pragma unroll
        for (int kk = 0; kk < 32; kk++) {
            const float4 a = *(const float4*)&as[kk][tm];
            const float4 b = *(const float4*)&bs[kk][tn];
            acc[0][0] += a.x * b.x; acc[0][1] += a.x * b.y; acc[0][2] += a.x * b.z; acc[0][3] += a.x * b.w;
            acc[1][0] += a.y * b.x; acc[1][1] += a.y * b.y; acc[1][2] += a.y * b.z; acc[1][3] += a.y * b.w;
            acc[2][0] += a.z * b.x; acc[2][1] += a.z * b.y; acc[2][2] += a.z * b.z; acc[2][3] += a.z * b.w;
            acc[3][0] += a.w * b.x; acc[3][1] += a.w * b.y; acc[3][2] += a.w * b.z; acc[3][3] += a.w * b.w;
        }
        __syncthreads();
    }

    // dump logits tile to LDS for gating (no global round-trip)
    #pragma unroll
    for (int i = 0; i < 4; i++)
        #pragma unroll
        for (int j = 0; j < 4; j++)
            lt[tm + i][tn + j] = acc[i][j];
    __syncthreads();

    // gating: 4 waves x 16 tokens, lane = expert
    const int wave = tid >> 6;
    const int lane = tid & 63;
    float gacc = 0.f;

    for (int i = 0; i < 16; i++) {
        const int tok = wave + i * 4;       // local token 0..63
        const int t = m0 + tok;
        const float logit = lt[tok][lane];

        // stable softmax across 64 lanes
        float m = logit;
        #pragma unroll
        for (int off = 32; off; off >>= 1) m = fmaxf(m, __shfl_xor(m, off));
        const float p = expf(logit - m);
        float s = p;
        #pragma unroll
        for (int off = 32; off; off >>= 1) s += __shfl_xor(s, off);
        const float gate = p / s;

        // argmax over logits, tie -> lowest index
        float v1 = logit; int b1 = lane;
        #pragma unroll
        for (int off = 32; off; off >>= 1) {
            float ov = __shfl_xor(v1, off); int oi = __shfl_xor(b1, off);
            if (ov > v1 || (ov == v1 && oi < b1)) { v1 = ov; b1 = oi; }
        }
        const int i1 = b1;

        // second: argmax of logits+gumbel, first masked
        float zz = logit + gumbel[(size_t)t * NEXP + lane];
        if (lane == i1) zz = -INFINITY;
        float v2 = zz; int b2 = lane;
        #pragma unroll
        for (int off = 32; off; off >>= 1) {
            float ov = __shfl_xor(v2, off); int oi = __shfl_xor(b2, off);
            if (ov > v2 || (ov == v2 && oi < b2)) { v2 = ov; b2 = oi; }
        }
        const int i2 = b2;

        const float gg1 = __shfl(gate, i1);
        const float gg2 = __shfl(gate, i2);
        if (lane == 0) { idx1[t] = i1; idx2[t] = i2; g1[t] = gg1; g2[t] = gg2; }
        gacc += gate;   // lane == expert column partial
    }

    sgs[wave][lane] = gacc;
    __syncthreads();
    if (tid < 64) {
        const float tsum = sgs[0][tid] + sgs[1][tid] + sgs[2][tid] + sgs[3][tid];
        bpart[(size_t)bid * 64 + tid] = tsum;   // deterministic partial
    }
}

// ============================================================
// K2: per-expert exclusive prefix counts, unrolled x4 to hide load latency.
// ============================================================
__global__ __launch_bounds__(64) void k_scan(const int* __restrict__ idx1, const int* __restrict__ idx2,
                                             int* __restrict__ loc1, int* __restrict__ loc2,
                                             float* __restrict__ ec_out, int* __restrict__ cnt1_buf) {
    const int e = blockIdx.x;
    const int lane = threadIdx.x;
    const unsigned long long below = (lane == 63) ? 0x7FFFFFFFFFFFFFFFULL : ((1ULL << lane) - 1ULL);

    int cnt = 0;
    for (int base = 0; base < NTOK; base += 256) {
        const int t = base + lane;
        const int a0 = idx1[t], a1 = idx1[t + 64], a2 = idx1[t + 128], a3 = idx1[t + 192];
        unsigned long long bal;
        bal = __ballot(a0 == e); if (a0 == e) loc1[t]       = cnt + __popcll(bal & below); cnt += __popcll(bal);
        bal = __ballot(a1 == e); if (a1 == e) loc1[t + 64]  = cnt + __popcll(bal & below); cnt += __popcll(bal);
        bal = __ballot(a2 == e); if (a2 == e) loc1[t + 128] = cnt + __popcll(bal & below); cnt += __popcll(bal);
        bal = __ballot(a3 == e); if (a3 == e) loc1[t + 192] = cnt + __popcll(bal & below); cnt += __popcll(bal);
    }
    if (lane == 0) { cnt1_buf[e] = cnt; ec_out[e] = (float)cnt; }
    const int cnt1_total = cnt;

    int c2 = cnt1_total;
    for (int base = 0; base < NTOK; base += 256) {
        const int t = base + lane;
        const int a0 = idx2[t], a1 = idx2[t + 64], a2 = idx2[t + 128], a3 = idx2[t + 192];
        unsigned long long bal;
        bal = __ballot(a0 == e); if (a0 == e) loc2[t]       = c2 + __popcll(bal & below); c2 += __popcll(bal);
        bal = __ballot(a1 == e); if (a1 == e) loc2[t + 64]  = c2 + __popcll(bal & below); c2 += __popcll(bal);
        bal = __ballot(a2 == e); if (a2 == e) loc2[t + 128] = c2 + __popcll(bal & below); c2 += __popcll(bal);
        bal = __ballot(a3 == e); if (a3 == e) loc2[t + 192] = c2 + __popcll(bal & below); c2 += __popcll(bal);
    }
}

// ============================================================
// K3: normalize (post-capacity, reference order) + sparse scatter.
// ============================================================
__global__ __launch_bounds__(256) void k_scatter(const int* __restrict__ idx1, const int* __restrict__ idx2,
                                                 const int* __restrict__ loc1, const int* __restrict__ loc2,
                                                 const float* __restrict__ g1, const float* __restrict__ g2,
                                                 float* __restrict__ out) {
    const int t = blockIdx.x * 256 + threadIdx.x;
    const int i1 = idx1[t], i2 = idx2[t];
    const int l1 = loc1[t], l2 = loc2[t];
    const bool k1 = (l1 < CAP), k2 = (l2 < CAP);
    const float ga = k1 ? g1[t] : 0.f;
    const float gb = k2 ? g2[t] : 0.f;
    const float denom = fmaxf(ga + gb, 1.1920928955078125e-07f);
    const float w1 = ga / denom;
    const float w2 = gb / denom;

    if (k1 && w1 != 0.f) {
        const size_t idx = (size_t)t * (NEXP * CAP) + (size_t)i1 * CAP + l1;
        out[OFF_CW + idx] = w1;
        out[OFF_DM + idx] = 1.0f;
    }
    if (k2 && w2 != 0.f) {
        const size_t idx = (size_t)t * (NEXP * CAP) + (size_t)i2 * CAP + l2;
        out[OFF_CW + idx] = w2;
        out[OFF_DM + idx] = 1.0f;
    }
}

// ============================================================
// K4: l_aux, fixed-order deterministic reduction.
// ============================================================
__global__ __launch_bounds__(64) void k_laux(const float* __restrict__ bpart,
                                             const int* __restrict__ cnt1,
                                             float* __restrict__ out) {
    const int lane = threadIdx.x;
    float s = 0.f;
    for (int b = 0; b < GEMM_BLOCKS; b++) s += bpart[(size_t)b * 64 + lane];
    float v = s * (float)cnt1[lane];
    #pragma unroll
    for (int off = 32; off; off >>= 1) v += __shfl_xor(v, off);
    if (lane == 0) out[0] = 64.0f * v / ((float)NTOK * (float)NTOK);
}

extern "C" void kernel_launch(void* const* d_in, const int* in_sizes, int n_in,
                              void* d_out, int out_size, void* d_ws, size_t ws_size,
                              hipStream_t stream) {
    const float* x      = (const float*)d_in[0];
    const float* w      = (const float*)d_in[1];
    const float* gumbel = (const float*)d_in[2];
    float* out = (float*)d_out;

    float* ws_f = (float*)d_ws;
    int*   ws_i = (int*)d_ws;

    int*   idx1   = ws_i + WS_IDX1;
    int*   idx2   = ws_i + WS_IDX2;
    float* g1     = ws_f + WS_G1;
    float* g2     = ws_f + WS_G2;
    int*   loc1   = ws_i + WS_LOC1;
    int*   loc2   = ws_i + WS_LOC2;
    float* bpart  = ws_f + WS_BPART;
    int*   cnt1   = ws_i + WS_CNT1;

    k_main<<<TOTAL_BLOCKS, 256, 0, stream>>>(x, w, gumbel, idx1, idx2, g1, g2, bpart, out);
    k_scan<<<NEXP, 64, 0, stream>>>(idx1, idx2, loc1, loc2, out + OFF_EC, cnt1);
    k_scatter<<<NTOK / 256, 256, 0, stream>>>(idx1, idx2, loc1, loc2, g1, g2, out);
    k_laux<<<1, 64, 0, stream>>>(bpart, cnt1, out);
}